// Round 15
// baseline (150.632 us; speedup 1.0000x reference)
//
#include <hip/hip_runtime.h>

typedef _Float16 f16x2 __attribute__((ext_vector_type(2)));
typedef __fp16  fp16x2 __attribute__((ext_vector_type(2)));

// Problem constants
constexpr int NKW  = 25, NK = 625;
constexpr int WPADR = 132;                  // reference padded width
constexpr int RST   = 35;                   // LDS row stride in uint2 (+1 anti-conflict)
constexpr int IMG   = 8;                    // images per block (weight reuse factor)
constexpr int NSLAB = 6;                    // ki slabs: NKI = {5,4,4,4,4,4}
constexpr int MAXR  = 30;                   // max staged rows (slab 0)

union U2H { unsigned int u; f16x2 h; fp16x2 p; };

__device__ __forceinline__ float dot2acc(unsigned int a, unsigned int b, float c) {
    U2H ua, ub; ua.u = a; ub.u = b;
#if __has_builtin(__builtin_amdgcn_fdot2)
    return __builtin_amdgcn_fdot2(ua.h, ub.h, c, false);
#else
    return c + (float)ua.h.x * (float)ub.h.x + (float)ua.h.y * (float)ub.h.y;
#endif
}

// SINGLE-KERNEL version of R14 (gather kernel deleted: its ~3-5 us of
// execution + launch gap + serialization was the last identified lever).
// Weights are built in-block from dense W via the same zero-padded 16-slot
// formula the gather used (values bit-identical): ~80 predicated scalar
// loads/thread from L3-resident W, once per block, amortized over 8 images,
// issued upfront so their latency overlaps the first x staging.
// Structure: R11 depth-2 register pipeline + R14 XCD-pinning swizzle;
// output k split across lane pair (l, l^32), alignment folded into
// zero-padded f16 weights (uniform 4x ds_read_b64 + 8x fdot2 per di row).
__global__ __launch_bounds__(256, 4)
void lc2d_pipe(const float* __restrict__ x, const float* __restrict__ Wfull,
               const float* __restrict__ bias, float* __restrict__ out) {
    __shared__ uint2 xs[2][MAXR * RST];     // 16800 B

    // swizzle: flat -> (grp, slab) with grp % 8 == flat % 8 (XCD-pinned)
    const int flat = blockIdx.x;            // 0..767
    const int xcd  = flat & 7;
    const int j_   = flat >> 3;             // 0..95
    const int grp  = xcd + 8 * (j_ & 15);   // 0..127
    const int slab = j_ >> 4;               // 0..5
    const int K0   = slab ? (4 * slab + 1) : 0;   // 0,5,9,13,17,21
    const int NKI  = slab ? 4 : 5;
    const int R    = 5 * NKI + 5;           // staged rows: 30 / 25
    const int NOUT = NKI * NKW;             // 125 / 100
    const int row0 = 5 * K0 - 2;            // unpadded row of staged idx 0
    const int tid  = threadIdx.x;
    const int b0   = grp * IMG;

    // pair mapping: wave w, lane l -> pair = w*32 + (l&31), half = (l>>5)&1
    const int lane = tid & 63;
    const int pairidx = (tid >> 6) * 32 + (lane & 31);
    const int half = (lane >> 5) & 1;
    const bool active = pairidx < NOUT;
    const int ki_l = pairidx / 25;
    const int kj   = pairidx - ki_l * 25;
    const int k    = (K0 + ki_l) * NKW + kj;
    const int di0  = half * 5;              // this thread's 5 di rows

    // ---- weights: built in-block from dense W, ONCE, amortized over 8 imgs.
    // wq[j] (j=0..9) holds padded halves 8j..8j+7 of this half's 5 di rows;
    // real data at in-row slot o..o+9, o = (5*kj+2)&3, matching the aligned
    // LDS window h0 = (5*kj+2)&~3. Runs of 25 consecutive k make the lane
    // pattern mostly contiguous -> few lines per wave-gather, L3-resident.
    uint4 wq[10];
    float bval = 0.f;
    if (active) {
        const int o = (5 * kj + 2) & 3;
#pragma unroll
        for (int j = 0; j < 10; ++j) {
            const int di = di0 + (j >> 1), pb = (j & 1) * 8;
            unsigned int uu[4];
#pragma unroll
            for (int m = 0; m < 4; ++m) {
                float f0 = 0.f, f1 = 0.f;
                const int j0 = pb + 2 * m - o, j1 = pb + 2 * m + 1 - o;
                const size_t rowb = (size_t)(((K0 + ki_l) * 5 + di) * WPADR + kj * 5);
                if (j0 >= 0 && j0 < 10) f0 = Wfull[(rowb + j0) * NK + k];
                if (j1 >= 0 && j1 < 10) f1 = Wfull[(rowb + j1) * NK + k];
                U2H u; u.p = __builtin_amdgcn_cvt_pkrtz(f0, f1);
                uu[m] = u.u;
            }
            wq[j] = make_uint4(uu[0], uu[1], uu[2], uu[3]);
        }
        if (half == 0) bval = bias[k];
    }

    // ---- boundary zeros, once, both buffers (q=0 left pad, q=33 right pad) ----
    for (int i = tid; i < 4 * R; i += 256)
        xs[i & 1][(i >> 2) * RST + ((i >> 1) & 1) * 33] = make_uint2(0u, 0u);

    // ---- pipeline phases ----
    auto stage_load = [&](int img, float4* tmp) {
        const float* xb = x + ((size_t)(b0 + img) << 14);
#pragma unroll
        for (int t = 0; t < 4; ++t) {
            const int i = tid + t * 256;
            tmp[t] = make_float4(0.f, 0.f, 0.f, 0.f);
            if (i < R * 32) {
                const int idx = i >> 5, q = i & 31;
                const int r = row0 + idx;
                if (r >= 0 && r < 128)
                    tmp[t] = *reinterpret_cast<const float4*>(xb + (r << 7) + (q << 2));
            }
        }
    };
    auto stage_write = [&](int buf, const float4* tmp) {
#pragma unroll
        for (int t = 0; t < 4; ++t) {
            const int i = tid + t * 256;
            if (i < R * 32) {
                const int idx = i >> 5, q = (i & 31) + 1;
                U2H u0, u1;
                u0.p = __builtin_amdgcn_cvt_pkrtz(tmp[t].x, tmp[t].y);
                u1.p = __builtin_amdgcn_cvt_pkrtz(tmp[t].z, tmp[t].w);
                xs[buf][idx * RST + q] = make_uint2(u0.u, u1.u);
            }
        }
    };

    // tmp[j&1] holds image j's loads. Prologue: img0 staged, img1 in flight.
    float4 tmpA[4], tmpB[4];
    stage_load(0, tmpA);
    stage_write(0, tmpA);
    stage_load(1, tmpB);
    __syncthreads();

    for (int i = 0; i < IMG; ++i) {
        // issue image i+2's loads into the tmp slot just freed (image i's)
        if (i + 2 < IMG) stage_load(i + 2, (i & 1) ? tmpB : tmpA);

        float acc0 = 0.f, acc1 = 0.f;
        if (active) {
            const uint2* base = xs[i & 1] + (5 * ki_l + di0) * RST + ((5 * kj + 2) >> 2);
#pragma unroll
            for (int d = 0; d < 5; ++d) {
                const uint2* rowp = base + d * RST;
                const uint2 a0 = rowp[0], a1 = rowp[1], a2 = rowp[2], a3 = rowp[3];
                const uint4 wA = wq[2 * d], wB = wq[2 * d + 1];
                acc0 = dot2acc(a0.x, wA.x, acc0);
                acc1 = dot2acc(a0.y, wA.y, acc1);
                acc0 = dot2acc(a1.x, wA.z, acc0);
                acc1 = dot2acc(a1.y, wA.w, acc1);
                acc0 = dot2acc(a2.x, wB.x, acc0);
                acc1 = dot2acc(a2.y, wB.y, acc1);
                acc0 = dot2acc(a3.x, wB.z, acc0);
                acc1 = dot2acc(a3.y, wB.w, acc1);
            }
        }
        // combine lane pair (l, l^32) within the wave; half 0 stores
        float acc = acc0 + acc1;
        float other = __shfl_xor(acc, 32, 64);
        if (active && half == 0)
            out[(size_t)(b0 + i) * NK + k] = acc + other + bval;

        // write image i+1 into the other LDS buffer; waits only its own loads
        if (i + 1 < IMG) stage_write((i + 1) & 1, (i & 1) ? tmpA : tmpB);
        __syncthreads();
    }
}

extern "C" void kernel_launch(void* const* d_in, const int* in_sizes, int n_in,
                              void* d_out, int out_size, void* d_ws, size_t ws_size,
                              hipStream_t stream) {
    const float* x    = (const float*)d_in[0];
    const float* W    = (const float*)d_in[1];
    const float* bias = (const float*)d_in[2];
    float* out = (float*)d_out;
    (void)d_ws; (void)ws_size;

    const dim3 grid(128 * NSLAB);           // 768 blocks, XCD-swizzled in-kernel
    lc2d_pipe<<<grid, 256, 0, stream>>>(x, W, bias, out);
}

// Round 16
// 122.374 us; speedup vs baseline: 1.2309x; 1.2309x over previous
//
#include <hip/hip_runtime.h>

typedef _Float16 f16x2 __attribute__((ext_vector_type(2)));
typedef __fp16  fp16x2 __attribute__((ext_vector_type(2)));

// Problem constants
constexpr int NKW  = 25, NK = 625;
constexpr int WPADR = 132;                  // reference padded width
constexpr int WPT   = 160;                  // padded halves per (ki,kj) weight row
constexpr int RST   = 35;                   // LDS row stride in uint2 (+1 anti-conflict)
constexpr int IMG   = 8;                    // images per block (weight reuse factor)
constexpr int NSLAB = 6;                    // ki slabs: NKI = {5,4,4,4,4,4}
constexpr int MAXR  = 30;                   // max staged rows (slab 0)

union U2H { unsigned int u; f16x2 h; fp16x2 p; };

// ---- gather: dense W -> f16 weights, zero-padded 16-slot rows, TRANSPOSED ----
// wgpT as uint4[20][625]; slot j of output k holds padded halves 8j..8j+7.
// Real data at in-row slot o..o+9, o = (5*kj+2) & 3, matching aligned LDS
// window h0 = (5*kj+2) & ~3.
// NOTE (R15 lesson): folding this into the main kernel spills wq to scratch
// (VGPR_Count dropped to 52, kernel 22->55 us). The separate gather keeps the
// main kernel's weight load a clean 10x coalesced-uint4 batch.
__global__ void gather_wp(const float* __restrict__ W, _Float16* __restrict__ wgpT) {
    int t = blockIdx.x * 256 + threadIdx.x;
    if (t >= NK * WPT) return;
    int k = t / WPT, p = t % WPT;
    int di = p >> 4, s = p & 15;
    int ki = k / NKW, kj = k % NKW;
    int o = (5 * kj + 2) & 3;
    int j = s - o;
    float val = 0.f;
    if (j >= 0 && j < 10)
        val = W[(size_t)((ki * 5 + di) * WPADR + kj * 5 + j) * NK + k];
    wgpT[((size_t)(p >> 3) * NK + k) * 8 + (p & 7)] = (_Float16)val;
}

__device__ __forceinline__ float dot2acc(unsigned int a, unsigned int b, float c) {
    U2H ua, ub; ua.u = a; ub.u = b;
#if __has_builtin(__builtin_amdgcn_fdot2)
    return __builtin_amdgcn_fdot2(ua.h, ub.h, c, false);
#else
    return c + (float)ua.h.x * (float)ub.h.x + (float)ua.h.y * (float)ub.h.y;
#endif
}

// R11 structure + XCD-PINNING SWIZZLE (measured best: 121.7 us total).
// All 6 ki-slabs of an image group get blocks with the same (flat % 8) ->
// same XCD, so band/halo re-reads of x hit that XCD's L2. Output k split
// across lane pair (l, l^32); weights 10 coalesced uint4/thread once per
// block; depth-2 register pipeline keeps two images' loads in flight.
template <bool USE_WG>
__global__ __launch_bounds__(256, 4)
void lc2d_pipe(const float* __restrict__ x, const _Float16* __restrict__ wgpT,
               const float* __restrict__ Wfull,
               const float* __restrict__ bias, float* __restrict__ out) {
    __shared__ uint2 xs[2][MAXR * RST];     // 16800 B

    // swizzle: flat -> (grp, slab) with grp % 8 == flat % 8 (XCD-pinned)
    const int flat = blockIdx.x;            // 0..767
    const int xcd  = flat & 7;
    const int j_   = flat >> 3;             // 0..95
    const int grp  = xcd + 8 * (j_ & 15);   // 0..127
    const int slab = j_ >> 4;               // 0..5
    const int K0   = slab ? (4 * slab + 1) : 0;   // 0,5,9,13,17,21
    const int NKI  = slab ? 4 : 5;
    const int R    = 5 * NKI + 5;           // staged rows: 30 / 25
    const int NOUT = NKI * NKW;             // 125 / 100
    const int row0 = 5 * K0 - 2;            // unpadded row of staged idx 0
    const int tid  = threadIdx.x;
    const int b0   = grp * IMG;

    // pair mapping: wave w, lane l -> pair = w*32 + (l&31), half = (l>>5)&1
    const int lane = tid & 63;
    const int pairidx = (tid >> 6) * 32 + (lane & 31);
    const int half = (lane >> 5) & 1;
    const bool active = pairidx < NOUT;
    const int ki_l = pairidx / 25;
    const int kj   = pairidx - ki_l * 25;
    const int k    = (K0 + ki_l) * NKW + kj;
    const int di0  = half * 5;              // this thread's 5 di rows

    // ---- weights: 10 coalesced uint4 per thread, ONCE per block ----
    uint4 wq[10];
    float bval = 0.f;
    if (active) {
        if (USE_WG) {
            const uint4* wt4 = reinterpret_cast<const uint4*>(wgpT);
#pragma unroll
            for (int j = 0; j < 10; ++j) wq[j] = wt4[(size_t)(half * 10 + j) * NK + k];
        } else {
            const int o = (5 * kj + 2) & 3;
#pragma unroll
            for (int j = 0; j < 10; ++j) {
                const int di = di0 + (j >> 1), pb = (j & 1) * 8;
                unsigned int uu[4];
#pragma unroll
                for (int m = 0; m < 4; ++m) {
                    float f0 = 0.f, f1 = 0.f;
                    const int j0 = pb + 2 * m - o, j1 = pb + 2 * m + 1 - o;
                    const size_t rowb = (size_t)(((K0 + ki_l) * 5 + di) * WPADR + kj * 5);
                    if (j0 >= 0 && j0 < 10) f0 = Wfull[(rowb + j0) * NK + k];
                    if (j1 >= 0 && j1 < 10) f1 = Wfull[(rowb + j1) * NK + k];
                    U2H u; u.p = __builtin_amdgcn_cvt_pkrtz(f0, f1);
                    uu[m] = u.u;
                }
                wq[j] = make_uint4(uu[0], uu[1], uu[2], uu[3]);
            }
        }
        if (half == 0) bval = bias[k];
    }

    // ---- boundary zeros, once, both buffers (q=0 left pad, q=33 right pad) ----
    for (int i = tid; i < 4 * R; i += 256)
        xs[i & 1][(i >> 2) * RST + ((i >> 1) & 1) * 33] = make_uint2(0u, 0u);

    // ---- pipeline phases ----
    auto stage_load = [&](int img, float4* tmp) {
        const float* xb = x + ((size_t)(b0 + img) << 14);
#pragma unroll
        for (int t = 0; t < 4; ++t) {
            const int i = tid + t * 256;
            tmp[t] = make_float4(0.f, 0.f, 0.f, 0.f);
            if (i < R * 32) {
                const int idx = i >> 5, q = i & 31;
                const int r = row0 + idx;
                if (r >= 0 && r < 128)
                    tmp[t] = *reinterpret_cast<const float4*>(xb + (r << 7) + (q << 2));
            }
        }
    };
    auto stage_write = [&](int buf, const float4* tmp) {
#pragma unroll
        for (int t = 0; t < 4; ++t) {
            const int i = tid + t * 256;
            if (i < R * 32) {
                const int idx = i >> 5, q = (i & 31) + 1;
                U2H u0, u1;
                u0.p = __builtin_amdgcn_cvt_pkrtz(tmp[t].x, tmp[t].y);
                u1.p = __builtin_amdgcn_cvt_pkrtz(tmp[t].z, tmp[t].w);
                xs[buf][idx * RST + q] = make_uint2(u0.u, u1.u);
            }
        }
    };

    // tmp[j&1] holds image j's loads. Prologue: img0 staged, img1 in flight.
    float4 tmpA[4], tmpB[4];
    stage_load(0, tmpA);
    stage_write(0, tmpA);
    stage_load(1, tmpB);
    __syncthreads();

    for (int i = 0; i < IMG; ++i) {
        // issue image i+2's loads into the tmp slot just freed (image i's)
        if (i + 2 < IMG) stage_load(i + 2, (i & 1) ? tmpB : tmpA);

        float acc0 = 0.f, acc1 = 0.f;
        if (active) {
            const uint2* base = xs[i & 1] + (5 * ki_l + di0) * RST + ((5 * kj + 2) >> 2);
#pragma unroll
            for (int d = 0; d < 5; ++d) {
                const uint2* rowp = base + d * RST;
                const uint2 a0 = rowp[0], a1 = rowp[1], a2 = rowp[2], a3 = rowp[3];
                const uint4 wA = wq[2 * d], wB = wq[2 * d + 1];
                acc0 = dot2acc(a0.x, wA.x, acc0);
                acc1 = dot2acc(a0.y, wA.y, acc1);
                acc0 = dot2acc(a1.x, wA.z, acc0);
                acc1 = dot2acc(a1.y, wA.w, acc1);
                acc0 = dot2acc(a2.x, wB.x, acc0);
                acc1 = dot2acc(a2.y, wB.y, acc1);
                acc0 = dot2acc(a3.x, wB.z, acc0);
                acc1 = dot2acc(a3.y, wB.w, acc1);
            }
        }
        // combine lane pair (l, l^32) within the wave; half 0 stores
        float acc = acc0 + acc1;
        float other = __shfl_xor(acc, 32, 64);
        if (active && half == 0)
            out[(size_t)(b0 + i) * NK + k] = acc + other + bval;

        // write image i+1 into the other LDS buffer; waits only its own loads
        if (i + 1 < IMG) stage_write((i + 1) & 1, (i & 1) ? tmpA : tmpB);
        __syncthreads();
    }
}

extern "C" void kernel_launch(void* const* d_in, const int* in_sizes, int n_in,
                              void* d_out, int out_size, void* d_ws, size_t ws_size,
                              hipStream_t stream) {
    const float* x    = (const float*)d_in[0];
    const float* W    = (const float*)d_in[1];
    const float* bias = (const float*)d_in[2];
    float* out = (float*)d_out;

    const dim3 grid(128 * NSLAB);           // 768 blocks, XCD-swizzled in-kernel
    if (ws_size >= (size_t)NK * WPT * sizeof(_Float16)) {
        _Float16* wgpT = (_Float16*)d_ws;
        gather_wp<<<(NK * WPT + 255) / 256, 256, 0, stream>>>(W, wgpT);
        lc2d_pipe<true><<<grid, 256, 0, stream>>>(x, wgpT, W, bias, out);
    } else {
        lc2d_pipe<false><<<grid, 256, 0, stream>>>(x, nullptr, W, bias, out);
    }
}